// Round 2
// baseline (766.968 us; speedup 1.0000x reference)
//
#include <hip/hip_runtime.h>
#include <math.h>

#define NOBJ  2048
#define EMBED 256
#define NHD   8     // heads
#define NPT   32    // points
#define HD    32    // head dim
#define NUMIMG 4
#define HH    160
#define WW    160
#define FFN   1024
#define PLANE (HH*WW)   // 25600
#define LN_EPS 1e-5f

// ---------------------------------------------------------------------------
// K1: offsets = obj_emb @ w_off + b_off; -> sample coords ix,iy per (n,h,p)
// 8 objects per block to amortize w_off (512KB) traffic across objects.
// ---------------------------------------------------------------------------
__global__ __launch_bounds__(256) void k_offsets(
    const float* __restrict__ obj_emb, const float* __restrict__ w_off,
    const float* __restrict__ b_off, const float* __restrict__ obj_xy,
    const float* __restrict__ strides,
    float* __restrict__ cx, float* __restrict__ cy) {
  const int G = 8;
  __shared__ float s_emb[G][EMBED];
  const int t = threadIdx.x;
  const int n0 = blockIdx.x * G;
  #pragma unroll
  for (int g = 0; g < G; ++g) s_emb[g][t] = obj_emb[(n0 + g) * EMBED + t];
  __syncthreads();

  float ax[G], ay[G];
  #pragma unroll
  for (int g = 0; g < G; ++g) { ax[g] = 0.f; ay[g] = 0.f; }

  const float2* wp = (const float2*)w_off;  // row = 256 float2
  for (int e = 0; e < EMBED; ++e) {
    float2 w = wp[e * 256 + t];
    #pragma unroll
    for (int g = 0; g < G; ++g) {
      float a = s_emb[g][e];
      ax[g] = fmaf(a, w.x, ax[g]);
      ay[g] = fmaf(a, w.y, ay[g]);
    }
  }
  const float bx = b_off[2 * t], by = b_off[2 * t + 1];
  #pragma unroll
  for (int g = 0; g < G; ++g) {
    const int n = n0 + g;
    const float st = strides[n];
    const float lx = obj_xy[2 * n]     + (ax[g] + bx) * st;
    const float ly = obj_xy[2 * n + 1] + (ay[g] + by) * st;
    const float gx = lx * (2.0f / (WW * 4)) - 1.0f;
    const float gy = ly * (2.0f / (HH * 4)) - 1.0f;
    const float ix = ((gx + 1.0f) * WW - 1.0f) * 0.5f;
    const float iy = ((gy + 1.0f) * HH - 1.0f) * 0.5f;
    cx[n * 256 + t] = ix;
    cy[n * 256 + t] = iy;
  }
}

// ---------------------------------------------------------------------------
// K2: bilinear sample k/v/x2d/mask, attention, softmax; write v/a/mask/x2d
// sample outputs + attention output row (ws_attn). One block per object.
// Thread t = (h,p): h=t>>5, p=t&31.
// ---------------------------------------------------------------------------
__global__ __launch_bounds__(256) void k_sample(
    const float* __restrict__ query, const float* __restrict__ key_feat,
    const float* __restrict__ value, const float* __restrict__ x2d,
    const float* __restrict__ x2d_mask, const int* __restrict__ obj_img,
    const float* __restrict__ cx, const float* __restrict__ cy,
    float* __restrict__ o_vs, float* __restrict__ o_as,
    float* __restrict__ o_ms, float* __restrict__ o_x2,
    float* __restrict__ ws_attn) {
  __shared__ float s_q[256];
  __shared__ float s_v[NHD * NPT * 33];  // [h][p][33] pad to kill bank conflicts
  __shared__ float s_asm[256];

  const int n = blockIdx.x;
  const int t = threadIdx.x;
  const int h = t >> 5, p = t & 31;

  s_q[t] = query[n * 256 + t];
  const int img = obj_img[n];
  const float ix = cx[n * 256 + t];
  const float iy = cy[n * 256 + t];

  const float x0f = floorf(ix), y0f = floorf(iy);
  const float wx1 = ix - x0f, wy1 = iy - y0f;
  const int x0 = (int)x0f, y0 = (int)y0f;
  const int x1 = x0 + 1, y1 = y0 + 1;
  const int x0c = min(max(x0, 0), WW - 1), x1c = min(max(x1, 0), WW - 1);
  const int y0c = min(max(y0, 0), HH - 1), y1c = min(max(y1, 0), HH - 1);
  const float w00 = (1.f - wx1) * (1.f - wy1);
  const float w10 = wx1 * (1.f - wy1);
  const float w01 = (1.f - wx1) * wy1;
  const float w11 = wx1 * wy1;
  const int o00 = y0c * WW + x0c, o10 = y0c * WW + x1c;
  const int o01 = y1c * WW + x0c, o11 = y1c * WW + x1c;

  const float* kb = key_feat + (size_t)(img * EMBED + h * HD) * PLANE;
  const float* vb = value    + (size_t)(img * EMBED + h * HD) * PLANE;
  __syncthreads();

  float a_acc = 0.f;
  float* svrow = &s_v[(h * NPT + p) * 33];
  float* vout = o_vs + (size_t)(n * NHD + h) * (HD * NPT) + p;
  for (int c = 0; c < HD; ++c) {
    const float* kc = kb + c * PLANE;
    const float kv = w00 * kc[o00] + w10 * kc[o10] + w01 * kc[o01] + w11 * kc[o11];
    a_acc = fmaf(s_q[h * HD + c], kv, a_acc);
    const float* vc = vb + c * PLANE;
    const float vv = w00 * vc[o00] + w10 * vc[o10] + w01 * vc[o01] + w11 * vc[o11];
    svrow[c] = vv;
    vout[c * NPT] = vv;  // v_samples[n,h,c,p] (transposed layout), coalesced in p
  }

  const float a = a_acc * 0.17677669529663687f;  // 1/sqrt(32)
  o_as[n * 256 + t] = a;

  // x2d (2ch, border pad)
  const float* xb0 = x2d + (size_t)img * 2 * PLANE;
  const float* xb1 = xb0 + PLANE;
  const float x2v0 = w00 * xb0[o00] + w10 * xb0[o10] + w01 * xb0[o01] + w11 * xb0[o11];
  const float x2v1 = w00 * xb1[o00] + w10 * xb1[o10] + w01 * xb1[o01] + w11 * xb1[o11];
  o_x2[(size_t)n * 512 + h * 64 + p]      = x2v0;
  o_x2[(size_t)n * 512 + h * 64 + 32 + p] = x2v1;

  // mask (1ch, zeros pad: zero weight for out-of-range taps)
  const float* mb = x2d_mask + (size_t)img * PLANE;
  const float m00 = (x0 >= 0 && x0 < WW && y0 >= 0 && y0 < HH) ? w00 : 0.f;
  const float m10 = (x1 >= 0 && x1 < WW && y0 >= 0 && y0 < HH) ? w10 : 0.f;
  const float m01 = (x0 >= 0 && x0 < WW && y1 >= 0 && y1 < HH) ? w01 : 0.f;
  const float m11 = (x1 >= 0 && x1 < WW && y1 >= 0 && y1 < HH) ? w11 : 0.f;
  const float m = m00 * mb[o00] + m10 * mb[o10] + m01 * mb[o01] + m11 * mb[o11];
  o_ms[n * 256 + t] = m;

  // softmax over p (32-lane groups)
  float mx = a;
  #pragma unroll
  for (int o = 16; o >= 1; o >>= 1) mx = fmaxf(mx, __shfl_xor(mx, o, 32));
  const float ev = expf(a - mx);
  float s = ev;
  #pragma unroll
  for (int o = 16; o >= 1; o >>= 1) s += __shfl_xor(s, o, 32);
  s_asm[t] = ev / s * m;
  __syncthreads();

  // out_attn[h,d] = sum_p a_sm[h,p] * v_s[h,p,d];  thread = (h, d=p slot)
  const int d = p;
  float o = 0.f;
  const float* svh = &s_v[h * NPT * 33];
  const float* amh = &s_asm[h * NPT];
  #pragma unroll
  for (int pp = 0; pp < NPT; ++pp) o = fmaf(amh[pp], svh[pp * 33 + d], o);
  ws_attn[n * 256 + t] = o;
}

// ---------------------------------------------------------------------------
// wave-per-row LN helper: rows of 256 cols live in s_y; wave wv handles
// rows 2wv, 2wv+1. Writes dst[(m0+row)*256 + col] = (x-m)*rstd*g + b.
// ---------------------------------------------------------------------------
__device__ __forceinline__ void ln_rows_write(
    float (*s_y)[EMBED + 8], int m0, const float* __restrict__ g,
    const float* __restrict__ b, float* __restrict__ dst, int tid) {
  const int wv = tid >> 6, ln = tid & 63;
  #pragma unroll
  for (int k = 0; k < 2; ++k) {
    const int rr = wv * 2 + k;
    const float v0 = s_y[rr][ln], v1 = s_y[rr][ln + 64];
    const float v2 = s_y[rr][ln + 128], v3 = s_y[rr][ln + 192];
    float sum = v0 + v1 + v2 + v3;
    #pragma unroll
    for (int o = 32; o >= 1; o >>= 1) sum += __shfl_xor(sum, o);
    const float mean = sum * (1.0f / EMBED);
    const float d0 = v0 - mean, d1 = v1 - mean, d2 = v2 - mean, d3 = v3 - mean;
    float ss = d0 * d0 + d1 * d1 + d2 * d2 + d3 * d3;
    #pragma unroll
    for (int o = 32; o >= 1; o >>= 1) ss += __shfl_xor(ss, o);
    const float rstd = rsqrtf(ss * (1.0f / EMBED) + LN_EPS);
    const size_t base = (size_t)(m0 + rr) * EMBED;
    dst[base + ln]       = d0 * rstd * g[ln]       + b[ln];
    dst[base + ln + 64]  = d1 * rstd * g[ln + 64]  + b[ln + 64];
    dst[base + ln + 128] = d2 * rstd * g[ln + 128] + b[ln + 128];
    dst[base + ln + 192] = d3 * rstd * g[ln + 192] + b[ln + 192];
  }
}

// ---------------------------------------------------------------------------
// K3: U = LN1(attn @ w_out + b_out + obj_emb). 8 rows x 256 cols per block.
// ---------------------------------------------------------------------------
__global__ __launch_bounds__(256) void k_mlp1(
    const float* __restrict__ attn, const float* __restrict__ w_out,
    const float* __restrict__ b_out, const float* __restrict__ obj_emb,
    const float* __restrict__ ln1_g, const float* __restrict__ ln1_b,
    float* __restrict__ U) {
  const int MT = 8;
  __shared__ float s_a[MT][EMBED];
  __shared__ float s_y[MT][EMBED + 8];
  const int t = threadIdx.x;
  const int m0 = blockIdx.x * MT;
  #pragma unroll
  for (int r = 0; r < MT; ++r) s_a[r][t] = attn[(m0 + r) * EMBED + t];
  __syncthreads();

  float acc[MT];
  #pragma unroll
  for (int r = 0; r < MT; ++r) acc[r] = 0.f;
  for (int e = 0; e < EMBED; ++e) {
    const float bv = w_out[e * EMBED + t];
    #pragma unroll
    for (int r = 0; r < MT; ++r) acc[r] = fmaf(s_a[r][e], bv, acc[r]);
  }
  const float bo = b_out[t];
  #pragma unroll
  for (int r = 0; r < MT; ++r)
    s_y[r][t] = acc[r] + bo + obj_emb[(m0 + r) * EMBED + t];
  __syncthreads();
  ln_rows_write(s_y, m0, ln1_g, ln1_b, U, t);
}

// ---------------------------------------------------------------------------
// K4: F = relu(U @ w1 + b1). Grid (M/8, FFN/256).
// ---------------------------------------------------------------------------
__global__ __launch_bounds__(256) void k_ffn1(
    const float* __restrict__ U, const float* __restrict__ w1,
    const float* __restrict__ b1, float* __restrict__ F) {
  const int MT = 8;
  __shared__ float s_a[MT][EMBED];
  const int t = threadIdx.x;
  const int m0 = blockIdx.x * MT;
  const int j = blockIdx.y * 256 + t;
  #pragma unroll
  for (int r = 0; r < MT; ++r) s_a[r][t] = U[(m0 + r) * EMBED + t];
  __syncthreads();

  float acc[MT];
  #pragma unroll
  for (int r = 0; r < MT; ++r) acc[r] = 0.f;
  for (int e = 0; e < EMBED; ++e) {
    const float bv = w1[e * FFN + j];
    #pragma unroll
    for (int r = 0; r < MT; ++r) acc[r] = fmaf(s_a[r][e], bv, acc[r]);
  }
  const float bb = b1[j];
  #pragma unroll
  for (int r = 0; r < MT; ++r)
    F[(m0 + r) * FFN + j] = fmaxf(acc[r] + bb, 0.f);
}

// ---------------------------------------------------------------------------
// K5: out = LN2(U + F @ w2 + b2). K=1024 staged in 4 chunks.
// ---------------------------------------------------------------------------
__global__ __launch_bounds__(256) void k_ffn2(
    const float* __restrict__ F, const float* __restrict__ w2,
    const float* __restrict__ b2, const float* __restrict__ U,
    const float* __restrict__ ln2_g, const float* __restrict__ ln2_b,
    float* __restrict__ out) {
  const int MT = 8;
  __shared__ float s_a[MT][256];
  __shared__ float s_y[MT][EMBED + 8];
  const int t = threadIdx.x;
  const int m0 = blockIdx.x * MT;

  float acc[MT];
  #pragma unroll
  for (int r = 0; r < MT; ++r) acc[r] = 0.f;

  for (int kc = 0; kc < FFN; kc += 256) {
    #pragma unroll
    for (int r = 0; r < MT; ++r) s_a[r][t] = F[(m0 + r) * FFN + kc + t];
    __syncthreads();
    for (int e = 0; e < 256; ++e) {
      const float bv = w2[(kc + e) * EMBED + t];
      #pragma unroll
      for (int r = 0; r < MT; ++r) acc[r] = fmaf(s_a[r][e], bv, acc[r]);
    }
    __syncthreads();
  }
  const float bb = b2[t];
  #pragma unroll
  for (int r = 0; r < MT; ++r)
    s_y[r][t] = acc[r] + bb + U[(m0 + r) * EMBED + t];
  __syncthreads();
  ln_rows_write(s_y, m0, ln2_g, ln2_b, out, t);
}

// ---------------------------------------------------------------------------
extern "C" void kernel_launch(void* const* d_in, const int* in_sizes, int n_in,
                              void* d_out, int out_size, void* d_ws, size_t ws_size,
                              hipStream_t stream) {
  const float* query    = (const float*)d_in[0];
  const float* obj_emb  = (const float*)d_in[1];
  const float* key_feat = (const float*)d_in[2];
  const float* value    = (const float*)d_in[3];
  const float* x2d      = (const float*)d_in[4];
  const float* x2d_mask = (const float*)d_in[5];
  const float* obj_xy   = (const float*)d_in[6];
  const float* strides  = (const float*)d_in[7];
  const int*   obj_img  = (const int*)d_in[8];
  const float* w_off    = (const float*)d_in[9];
  const float* b_off    = (const float*)d_in[10];
  const float* w_out    = (const float*)d_in[11];
  const float* b_out    = (const float*)d_in[12];
  const float* ln1_g    = (const float*)d_in[13];
  const float* ln1_b    = (const float*)d_in[14];
  const float* w1       = (const float*)d_in[15];
  const float* b1       = (const float*)d_in[16];
  const float* w2       = (const float*)d_in[17];
  const float* b2       = (const float*)d_in[18];
  const float* ln2_g    = (const float*)d_in[19];
  const float* ln2_b    = (const float*)d_in[20];

  float* out = (float*)d_out;
  // Output sizes (return order):
  //   out          (2048,256)       =   524288
  //   v_samples    (2048,8,32,32)   = 16777216
  //   a_samples    (2048,8,1,32)    =   524288
  //   mask_samples (2048,8,1,32)    =   524288
  //   x2d_samples  (2048,8,2,32)    =  1048576
  float* o_out = out;
  float* o_vs  = out + 524288;
  float* o_as  = out + 524288 + 16777216;            // 17301504
  float* o_ms  = out + 524288 + 16777216 + 524288;   // 17825792
  float* o_x2  = out + 524288 + 16777216 + 1048576;  // 18350080

  float* ws = (float*)d_ws;
  float* cx   = ws;                   // 524288
  float* cy   = cx + 524288;          // 524288
  float* attn = cy + 524288;          // 524288
  float* U    = attn + 524288;        // 524288
  float* F    = U + 524288;           // 2097152  (total 16 MB)

  k_offsets<<<NOBJ / 8, 256, 0, stream>>>(obj_emb, w_off, b_off, obj_xy,
                                          strides, cx, cy);
  k_sample<<<NOBJ, 256, 0, stream>>>(query, key_feat, value, x2d, x2d_mask,
                                     obj_img, cx, cy, o_vs, o_as, o_ms, o_x2,
                                     attn);
  k_mlp1<<<NOBJ / 8, 256, 0, stream>>>(attn, w_out, b_out, obj_emb, ln1_g,
                                       ln1_b, U);
  k_ffn1<<<dim3(NOBJ / 8, FFN / 256), 256, 0, stream>>>(U, w1, b1, F);
  k_ffn2<<<NOBJ / 8, 256, 0, stream>>>(F, w2, b2, U, ln2_g, ln2_b, o_out);
}

// Round 3
// 600.252 us; speedup vs baseline: 1.2777x; 1.2777x over previous
//
#include <hip/hip_runtime.h>
#include <hip/hip_fp16.h>
#include <math.h>

#define NOBJ  2048
#define EMBED 256
#define NHD   8     // heads
#define NPT   32    // points
#define HD    32    // head dim
#define NUMIMG 4
#define HH    160
#define WW    160
#define FFN   1024
#define PLANE (HH*WW)   // 25600
#define LN_EPS 1e-5f

// ---------------------------------------------------------------------------
// K1: offsets = obj_emb @ w_off + b_off; -> sample coords ix,iy per (n,h,p)
// ---------------------------------------------------------------------------
__global__ __launch_bounds__(256) void k_offsets(
    const float* __restrict__ obj_emb, const float* __restrict__ w_off,
    const float* __restrict__ b_off, const float* __restrict__ obj_xy,
    const float* __restrict__ strides,
    float* __restrict__ cx, float* __restrict__ cy) {
  const int G = 8;
  __shared__ float s_emb[G][EMBED];
  const int t = threadIdx.x;
  const int n0 = blockIdx.x * G;
  #pragma unroll
  for (int g = 0; g < G; ++g) s_emb[g][t] = obj_emb[(n0 + g) * EMBED + t];
  __syncthreads();

  float ax[G], ay[G];
  #pragma unroll
  for (int g = 0; g < G; ++g) { ax[g] = 0.f; ay[g] = 0.f; }

  const float2* wp = (const float2*)w_off;  // row = 256 float2
  for (int e = 0; e < EMBED; ++e) {
    float2 w = wp[e * 256 + t];
    #pragma unroll
    for (int g = 0; g < G; ++g) {
      float a = s_emb[g][e];
      ax[g] = fmaf(a, w.x, ax[g]);
      ay[g] = fmaf(a, w.y, ay[g]);
    }
  }
  const float bx = b_off[2 * t], by = b_off[2 * t + 1];
  #pragma unroll
  for (int g = 0; g < G; ++g) {
    const int n = n0 + g;
    const float st = strides[n];
    const float lx = obj_xy[2 * n]     + (ax[g] + bx) * st;
    const float ly = obj_xy[2 * n + 1] + (ay[g] + by) * st;
    const float gx = lx * (2.0f / (WW * 4)) - 1.0f;
    const float gy = ly * (2.0f / (HH * 4)) - 1.0f;
    const float ix = ((gx + 1.0f) * WW - 1.0f) * 0.5f;
    const float iy = ((gy + 1.0f) * HH - 1.0f) * 0.5f;
    cx[n * 256 + t] = ix;
    cy[n * 256 + t] = iy;
  }
}

// ---------------------------------------------------------------------------
// K-relayout: key_feat/value (img,c,y,x) f32 -> kvh (img,y,x,kv,c) f16.
// Pixel block = 512 halfs (k[256] then v[256]) = 1024 B; a head slice is
// 64 B aligned-contiguous. Coalesced reads; 16 B-contiguous writes.
// ---------------------------------------------------------------------------
__global__ __launch_bounds__(256) void k_relayout(
    const float* __restrict__ key_feat, const float* __restrict__ value,
    __half* __restrict__ kvh) {
  __shared__ float s[64][33];
  const int t = threadIdx.x;
  const int xt  = blockIdx.x;   // 0..4  (x tile of 32)
  const int y   = blockIdx.y;   // 0..159
  const int img = blockIdx.z;   // 0..3
  const int xl = t & 31, cgrp = t >> 5;   // load map: 8 c-groups x 32 x
  const int xw = t >> 3, cw = t & 7;      // write map: 32 x x 8 c-groups

  for (int kv = 0; kv < 2; ++kv) {
    const float* src = kv ? value : key_feat;
    for (int ct = 0; ct < 4; ++ct) {
      #pragma unroll
      for (int i = 0; i < 8; ++i) {
        const int c = ct * 64 + cgrp * 8 + i;
        s[cgrp * 8 + i][xl] =
            src[((size_t)(img * 256 + c)) * PLANE + y * WW + xt * 32 + xl];
      }
      __syncthreads();
      __half h8[8];
      #pragma unroll
      for (int j = 0; j < 8; ++j) h8[j] = __float2half(s[cw * 8 + j][xw]);
      const size_t ob = ((size_t)(img * PLANE + y * WW + xt * 32 + xw)) * 512
                        + kv * 256 + ct * 64 + cw * 8;
      *(int4*)(kvh + ob) = *(const int4*)h8;
      __syncthreads();
    }
  }
}

// ---------------------------------------------------------------------------
// helper: accumulate 8 f16 channels (one int4) scaled by w into acc[8]
// ---------------------------------------------------------------------------
__device__ __forceinline__ void acc8(int4 r, float w, float* acc) {
  const __half2* hp = (const __half2*)&r;
  #pragma unroll
  for (int i = 0; i < 4; ++i) {
    const float2 f = __half22float2(hp[i]);
    acc[2 * i]     = fmaf(w, f.x, acc[2 * i]);
    acc[2 * i + 1] = fmaf(w, f.y, acc[2 * i + 1]);
  }
}

// ---------------------------------------------------------------------------
// K2 (fast): sample from f16 HWC kv layout. One block per object,
// thread t=(h,p). Per tap: 4x int4 (k) + 4x int4 (v) chunked by 8 channels.
// ---------------------------------------------------------------------------
__global__ __launch_bounds__(256) void k_sample_hwc(
    const float* __restrict__ query, const __half* __restrict__ kvh,
    const float* __restrict__ x2d, const float* __restrict__ x2d_mask,
    const int* __restrict__ obj_img,
    const float* __restrict__ cx, const float* __restrict__ cy,
    float* __restrict__ o_vs, float* __restrict__ o_as,
    float* __restrict__ o_ms, float* __restrict__ o_x2,
    float* __restrict__ ws_attn) {
  __shared__ float s_q[256];
  __shared__ float s_v[NHD * NPT * 33];
  __shared__ float s_asm[256];

  const int n = blockIdx.x;
  const int t = threadIdx.x;
  const int h = t >> 5, p = t & 31;

  s_q[t] = query[n * 256 + t];
  const int img = obj_img[n];
  const float ix = cx[n * 256 + t];
  const float iy = cy[n * 256 + t];

  const float x0f = floorf(ix), y0f = floorf(iy);
  const float wx1 = ix - x0f, wy1 = iy - y0f;
  const int x0 = (int)x0f, y0 = (int)y0f;
  const int x1 = x0 + 1, y1 = y0 + 1;
  const int x0c = min(max(x0, 0), WW - 1), x1c = min(max(x1, 0), WW - 1);
  const int y0c = min(max(y0, 0), HH - 1), y1c = min(max(y1, 0), HH - 1);
  const float w00 = (1.f - wx1) * (1.f - wy1);
  const float w10 = wx1 * (1.f - wy1);
  const float w01 = (1.f - wx1) * wy1;
  const float w11 = wx1 * wy1;
  const int o00 = y0c * WW + x0c, o10 = y0c * WW + x1c;
  const int o01 = y1c * WW + x0c, o11 = y1c * WW + x1c;

  const size_t pb = (size_t)img * PLANE;
  const int4* base = (const int4*)kvh;  // pixel = 64 int4: k[0..31], v[32..63]
  const long b0 = ((long)(pb + o00)) * 64 + h * 4;
  const long b1 = ((long)(pb + o10)) * 64 + h * 4;
  const long b2 = ((long)(pb + o01)) * 64 + h * 4;
  const long b3 = ((long)(pb + o11)) * 64 + h * 4;
  __syncthreads();

  float a_acc = 0.f;
  float* svrow = &s_v[(h * NPT + p) * 33];
  float* vout = o_vs + (size_t)(n * NHD + h) * (HD * NPT) + p;
  #pragma unroll
  for (int ch = 0; ch < 4; ++ch) {
    const int4 k0 = base[b0 + ch],      k1 = base[b1 + ch];
    const int4 k2 = base[b2 + ch],      k3 = base[b3 + ch];
    const int4 v0 = base[b0 + 32 + ch], v1 = base[b1 + 32 + ch];
    const int4 v2 = base[b2 + 32 + ch], v3 = base[b3 + 32 + ch];
    float kc[8] = {0, 0, 0, 0, 0, 0, 0, 0};
    float vc[8] = {0, 0, 0, 0, 0, 0, 0, 0};
    acc8(k0, w00, kc); acc8(k1, w10, kc); acc8(k2, w01, kc); acc8(k3, w11, kc);
    acc8(v0, w00, vc); acc8(v1, w10, vc); acc8(v2, w01, vc); acc8(v3, w11, vc);
    #pragma unroll
    for (int j = 0; j < 8; ++j) {
      const int c = ch * 8 + j;
      a_acc = fmaf(s_q[h * HD + c], kc[j], a_acc);
      svrow[c] = vc[j];
      vout[c * NPT] = vc[j];
    }
  }

  const float a = a_acc * 0.17677669529663687f;  // 1/sqrt(32)
  o_as[n * 256 + t] = a;

  // x2d (2ch, border pad) from original f32
  const float* xb0 = x2d + (size_t)img * 2 * PLANE;
  const float* xb1 = xb0 + PLANE;
  const float x2v0 = w00 * xb0[o00] + w10 * xb0[o10] + w01 * xb0[o01] + w11 * xb0[o11];
  const float x2v1 = w00 * xb1[o00] + w10 * xb1[o10] + w01 * xb1[o01] + w11 * xb1[o11];
  o_x2[(size_t)n * 512 + h * 64 + p]      = x2v0;
  o_x2[(size_t)n * 512 + h * 64 + 32 + p] = x2v1;

  // mask (1ch, zeros pad)
  const float* mb = x2d_mask + (size_t)img * PLANE;
  const float m00 = (x0 >= 0 && x0 < WW && y0 >= 0 && y0 < HH) ? w00 : 0.f;
  const float m10 = (x1 >= 0 && x1 < WW && y0 >= 0 && y0 < HH) ? w10 : 0.f;
  const float m01 = (x0 >= 0 && x0 < WW && y1 >= 0 && y1 < HH) ? w01 : 0.f;
  const float m11 = (x1 >= 0 && x1 < WW && y1 >= 0 && y1 < HH) ? w11 : 0.f;
  const float m = m00 * mb[o00] + m10 * mb[o10] + m01 * mb[o01] + m11 * mb[o11];
  o_ms[n * 256 + t] = m;

  // softmax over p (32-lane groups)
  float mx = a;
  #pragma unroll
  for (int o = 16; o >= 1; o >>= 1) mx = fmaxf(mx, __shfl_xor(mx, o, 32));
  const float ev = expf(a - mx);
  float s = ev;
  #pragma unroll
  for (int o = 16; o >= 1; o >>= 1) s += __shfl_xor(s, o, 32);
  s_asm[t] = ev / s * m;
  __syncthreads();

  const int d = p;
  float o = 0.f;
  const float* svh = &s_v[h * NPT * 33];
  const float* amh = &s_asm[h * NPT];
  #pragma unroll
  for (int pp = 0; pp < NPT; ++pp) o = fmaf(amh[pp], svh[pp * 33 + d], o);
  ws_attn[n * 256 + t] = o;
}

// ---------------------------------------------------------------------------
// K2 (fallback): original scalar-gather sampler (used if ws too small)
// ---------------------------------------------------------------------------
__global__ __launch_bounds__(256) void k_sample(
    const float* __restrict__ query, const float* __restrict__ key_feat,
    const float* __restrict__ value, const float* __restrict__ x2d,
    const float* __restrict__ x2d_mask, const int* __restrict__ obj_img,
    const float* __restrict__ cx, const float* __restrict__ cy,
    float* __restrict__ o_vs, float* __restrict__ o_as,
    float* __restrict__ o_ms, float* __restrict__ o_x2,
    float* __restrict__ ws_attn) {
  __shared__ float s_q[256];
  __shared__ float s_v[NHD * NPT * 33];
  __shared__ float s_asm[256];

  const int n = blockIdx.x;
  const int t = threadIdx.x;
  const int h = t >> 5, p = t & 31;

  s_q[t] = query[n * 256 + t];
  const int img = obj_img[n];
  const float ix = cx[n * 256 + t];
  const float iy = cy[n * 256 + t];

  const float x0f = floorf(ix), y0f = floorf(iy);
  const float wx1 = ix - x0f, wy1 = iy - y0f;
  const int x0 = (int)x0f, y0 = (int)y0f;
  const int x1 = x0 + 1, y1 = y0 + 1;
  const int x0c = min(max(x0, 0), WW - 1), x1c = min(max(x1, 0), WW - 1);
  const int y0c = min(max(y0, 0), HH - 1), y1c = min(max(y1, 0), HH - 1);
  const float w00 = (1.f - wx1) * (1.f - wy1);
  const float w10 = wx1 * (1.f - wy1);
  const float w01 = (1.f - wx1) * wy1;
  const float w11 = wx1 * wy1;
  const int o00 = y0c * WW + x0c, o10 = y0c * WW + x1c;
  const int o01 = y1c * WW + x0c, o11 = y1c * WW + x1c;

  const float* kb = key_feat + (size_t)(img * EMBED + h * HD) * PLANE;
  const float* vb = value    + (size_t)(img * EMBED + h * HD) * PLANE;
  __syncthreads();

  float a_acc = 0.f;
  float* svrow = &s_v[(h * NPT + p) * 33];
  float* vout = o_vs + (size_t)(n * NHD + h) * (HD * NPT) + p;
  for (int c = 0; c < HD; ++c) {
    const float* kc = kb + c * PLANE;
    const float kv = w00 * kc[o00] + w10 * kc[o10] + w01 * kc[o01] + w11 * kc[o11];
    a_acc = fmaf(s_q[h * HD + c], kv, a_acc);
    const float* vc = vb + c * PLANE;
    const float vv = w00 * vc[o00] + w10 * vc[o10] + w01 * vc[o01] + w11 * vc[o11];
    svrow[c] = vv;
    vout[c * NPT] = vv;
  }

  const float a = a_acc * 0.17677669529663687f;
  o_as[n * 256 + t] = a;

  const float* xb0 = x2d + (size_t)img * 2 * PLANE;
  const float* xb1 = xb0 + PLANE;
  const float x2v0 = w00 * xb0[o00] + w10 * xb0[o10] + w01 * xb0[o01] + w11 * xb0[o11];
  const float x2v1 = w00 * xb1[o00] + w10 * xb1[o10] + w01 * xb1[o01] + w11 * xb1[o11];
  o_x2[(size_t)n * 512 + h * 64 + p]      = x2v0;
  o_x2[(size_t)n * 512 + h * 64 + 32 + p] = x2v1;

  const float* mb = x2d_mask + (size_t)img * PLANE;
  const float m00 = (x0 >= 0 && x0 < WW && y0 >= 0 && y0 < HH) ? w00 : 0.f;
  const float m10 = (x1 >= 0 && x1 < WW && y0 >= 0 && y0 < HH) ? w10 : 0.f;
  const float m01 = (x0 >= 0 && x0 < WW && y1 >= 0 && y1 < HH) ? w01 : 0.f;
  const float m11 = (x1 >= 0 && x1 < WW && y1 >= 0 && y1 < HH) ? w11 : 0.f;
  const float m = m00 * mb[o00] + m10 * mb[o10] + m01 * mb[o01] + m11 * mb[o11];
  o_ms[n * 256 + t] = m;

  float mx = a;
  #pragma unroll
  for (int o = 16; o >= 1; o >>= 1) mx = fmaxf(mx, __shfl_xor(mx, o, 32));
  const float ev = expf(a - mx);
  float s = ev;
  #pragma unroll
  for (int o = 16; o >= 1; o >>= 1) s += __shfl_xor(s, o, 32);
  s_asm[t] = ev / s * m;
  __syncthreads();

  const int d = p;
  float o = 0.f;
  const float* svh = &s_v[h * NPT * 33];
  const float* amh = &s_asm[h * NPT];
  #pragma unroll
  for (int pp = 0; pp < NPT; ++pp) o = fmaf(amh[pp], svh[pp * 33 + d], o);
  ws_attn[n * 256 + t] = o;
}

// ---------------------------------------------------------------------------
// wave-per-row LN helper
// ---------------------------------------------------------------------------
__device__ __forceinline__ void ln_rows_write(
    float (*s_y)[EMBED + 8], int m0, const float* __restrict__ g,
    const float* __restrict__ b, float* __restrict__ dst, int tid) {
  const int wv = tid >> 6, ln = tid & 63;
  #pragma unroll
  for (int k = 0; k < 2; ++k) {
    const int rr = wv * 2 + k;
    const float v0 = s_y[rr][ln], v1 = s_y[rr][ln + 64];
    const float v2 = s_y[rr][ln + 128], v3 = s_y[rr][ln + 192];
    float sum = v0 + v1 + v2 + v3;
    #pragma unroll
    for (int o = 32; o >= 1; o >>= 1) sum += __shfl_xor(sum, o);
    const float mean = sum * (1.0f / EMBED);
    const float d0 = v0 - mean, d1 = v1 - mean, d2 = v2 - mean, d3 = v3 - mean;
    float ss = d0 * d0 + d1 * d1 + d2 * d2 + d3 * d3;
    #pragma unroll
    for (int o = 32; o >= 1; o >>= 1) ss += __shfl_xor(ss, o);
    const float rstd = rsqrtf(ss * (1.0f / EMBED) + LN_EPS);
    const size_t base = (size_t)(m0 + rr) * EMBED;
    dst[base + ln]       = d0 * rstd * g[ln]       + b[ln];
    dst[base + ln + 64]  = d1 * rstd * g[ln + 64]  + b[ln + 64];
    dst[base + ln + 128] = d2 * rstd * g[ln + 128] + b[ln + 128];
    dst[base + ln + 192] = d3 * rstd * g[ln + 192] + b[ln + 192];
  }
}

// ---------------------------------------------------------------------------
// K3: U = LN1(attn @ w_out + b_out + obj_emb)
// ---------------------------------------------------------------------------
__global__ __launch_bounds__(256) void k_mlp1(
    const float* __restrict__ attn, const float* __restrict__ w_out,
    const float* __restrict__ b_out, const float* __restrict__ obj_emb,
    const float* __restrict__ ln1_g, const float* __restrict__ ln1_b,
    float* __restrict__ U) {
  const int MT = 8;
  __shared__ float s_a[MT][EMBED];
  __shared__ float s_y[MT][EMBED + 8];
  const int t = threadIdx.x;
  const int m0 = blockIdx.x * MT;
  #pragma unroll
  for (int r = 0; r < MT; ++r) s_a[r][t] = attn[(m0 + r) * EMBED + t];
  __syncthreads();

  float acc[MT];
  #pragma unroll
  for (int r = 0; r < MT; ++r) acc[r] = 0.f;
  for (int e = 0; e < EMBED; ++e) {
    const float bv = w_out[e * EMBED + t];
    #pragma unroll
    for (int r = 0; r < MT; ++r) acc[r] = fmaf(s_a[r][e], bv, acc[r]);
  }
  const float bo = b_out[t];
  #pragma unroll
  for (int r = 0; r < MT; ++r)
    s_y[r][t] = acc[r] + bo + obj_emb[(m0 + r) * EMBED + t];
  __syncthreads();
  ln_rows_write(s_y, m0, ln1_g, ln1_b, U, t);
}

// ---------------------------------------------------------------------------
// K4: F = relu(U @ w1 + b1)
// ---------------------------------------------------------------------------
__global__ __launch_bounds__(256) void k_ffn1(
    const float* __restrict__ U, const float* __restrict__ w1,
    const float* __restrict__ b1, float* __restrict__ F) {
  const int MT = 8;
  __shared__ float s_a[MT][EMBED];
  const int t = threadIdx.x;
  const int m0 = blockIdx.x * MT;
  const int j = blockIdx.y * 256 + t;
  #pragma unroll
  for (int r = 0; r < MT; ++r) s_a[r][t] = U[(m0 + r) * EMBED + t];
  __syncthreads();

  float acc[MT];
  #pragma unroll
  for (int r = 0; r < MT; ++r) acc[r] = 0.f;
  for (int e = 0; e < EMBED; ++e) {
    const float bv = w1[e * FFN + j];
    #pragma unroll
    for (int r = 0; r < MT; ++r) acc[r] = fmaf(s_a[r][e], bv, acc[r]);
  }
  const float bb = b1[j];
  #pragma unroll
  for (int r = 0; r < MT; ++r)
    F[(m0 + r) * FFN + j] = fmaxf(acc[r] + bb, 0.f);
}

// ---------------------------------------------------------------------------
// K5: out = LN2(U + F @ w2 + b2)
// ---------------------------------------------------------------------------
__global__ __launch_bounds__(256) void k_ffn2(
    const float* __restrict__ F, const float* __restrict__ w2,
    const float* __restrict__ b2, const float* __restrict__ U,
    const float* __restrict__ ln2_g, const float* __restrict__ ln2_b,
    float* __restrict__ out) {
  const int MT = 8;
  __shared__ float s_a[MT][256];
  __shared__ float s_y[MT][EMBED + 8];
  const int t = threadIdx.x;
  const int m0 = blockIdx.x * MT;

  float acc[MT];
  #pragma unroll
  for (int r = 0; r < MT; ++r) acc[r] = 0.f;

  for (int kc = 0; kc < FFN; kc += 256) {
    #pragma unroll
    for (int r = 0; r < MT; ++r) s_a[r][t] = F[(m0 + r) * FFN + kc + t];
    __syncthreads();
    for (int e = 0; e < 256; ++e) {
      const float bv = w2[(kc + e) * EMBED + t];
      #pragma unroll
      for (int r = 0; r < MT; ++r) acc[r] = fmaf(s_a[r][e], bv, acc[r]);
    }
    __syncthreads();
  }
  const float bb = b2[t];
  #pragma unroll
  for (int r = 0; r < MT; ++r)
    s_y[r][t] = acc[r] + bb + U[(m0 + r) * EMBED + t];
  __syncthreads();
  ln_rows_write(s_y, m0, ln2_g, ln2_b, out, t);
}

// ---------------------------------------------------------------------------
extern "C" void kernel_launch(void* const* d_in, const int* in_sizes, int n_in,
                              void* d_out, int out_size, void* d_ws, size_t ws_size,
                              hipStream_t stream) {
  const float* query    = (const float*)d_in[0];
  const float* obj_emb  = (const float*)d_in[1];
  const float* key_feat = (const float*)d_in[2];
  const float* value    = (const float*)d_in[3];
  const float* x2d      = (const float*)d_in[4];
  const float* x2d_mask = (const float*)d_in[5];
  const float* obj_xy   = (const float*)d_in[6];
  const float* strides  = (const float*)d_in[7];
  const int*   obj_img  = (const int*)d_in[8];
  const float* w_off    = (const float*)d_in[9];
  const float* b_off    = (const float*)d_in[10];
  const float* w_out    = (const float*)d_in[11];
  const float* b_out    = (const float*)d_in[12];
  const float* ln1_g    = (const float*)d_in[13];
  const float* ln1_b    = (const float*)d_in[14];
  const float* w1       = (const float*)d_in[15];
  const float* b1       = (const float*)d_in[16];
  const float* w2       = (const float*)d_in[17];
  const float* b2       = (const float*)d_in[18];
  const float* ln2_g    = (const float*)d_in[19];
  const float* ln2_b    = (const float*)d_in[20];

  float* out = (float*)d_out;
  float* o_out = out;
  float* o_vs  = out + 524288;                       // (2048,8,32,32)
  float* o_as  = out + 524288 + 16777216;            // 17301504
  float* o_ms  = out + 524288 + 16777216 + 524288;   // 17825792
  float* o_x2  = out + 524288 + 16777216 + 1048576;  // 18350080

  // workspace plan: [kvh f16 104857600 B][cx|cy|attn|U|F f32 16777216 B]
  const size_t KVH_BYTES = (size_t)NUMIMG * PLANE * 512 * sizeof(__half);
  const size_t F32_BYTES = (size_t)4194304 * sizeof(float);
  const bool fast = ws_size >= KVH_BYTES + F32_BYTES;

  __half* kvh = (__half*)d_ws;
  float* fb = fast ? (float*)((char*)d_ws + KVH_BYTES) : (float*)d_ws;
  float* cx   = fb;
  float* cy   = cx + 524288;
  float* attn = cy + 524288;
  float* U    = attn + 524288;
  float* F    = U + 524288;

  k_offsets<<<NOBJ / 8, 256, 0, stream>>>(obj_emb, w_off, b_off, obj_xy,
                                          strides, cx, cy);
  if (fast) {
    k_relayout<<<dim3(5, HH, NUMIMG), 256, 0, stream>>>(key_feat, value, kvh);
    k_sample_hwc<<<NOBJ, 256, 0, stream>>>(query, kvh, x2d, x2d_mask, obj_img,
                                           cx, cy, o_vs, o_as, o_ms, o_x2,
                                           attn);
  } else {
    k_sample<<<NOBJ, 256, 0, stream>>>(query, key_feat, value, x2d, x2d_mask,
                                       obj_img, cx, cy, o_vs, o_as, o_ms, o_x2,
                                       attn);
  }
  k_mlp1<<<NOBJ / 8, 256, 0, stream>>>(attn, w_out, b_out, obj_emb, ln1_g,
                                       ln1_b, U);
  k_ffn1<<<dim3(NOBJ / 8, FFN / 256), 256, 0, stream>>>(U, w1, b1, F);
  k_ffn2<<<NOBJ / 8, 256, 0, stream>>>(F, w2, b2, U, ln2_g, ln2_b, o_out);
}

// Round 4
// 463.659 us; speedup vs baseline: 1.6542x; 1.2946x over previous
//
#include <hip/hip_runtime.h>
#include <hip/hip_fp16.h>
#include <math.h>

#define NOBJ  2048
#define EMBED 256
#define NHD   8     // heads
#define NPT   32    // points
#define HD    32    // head dim
#define NUMIMG 4
#define HH    160
#define WW    160
#define FFN   1024
#define PLANE (HH*WW)   // 25600
#define LN_EPS 1e-5f

typedef _Float16 f16x8 __attribute__((ext_vector_type(8)));
typedef float f32x4 __attribute__((ext_vector_type(4)));

// ---------------------------------------------------------------------------
// K1: offsets = obj_emb @ w_off + b_off; -> sample coords ix,iy per (n,h,p)
// ---------------------------------------------------------------------------
__global__ __launch_bounds__(256) void k_offsets(
    const float* __restrict__ obj_emb, const float* __restrict__ w_off,
    const float* __restrict__ b_off, const float* __restrict__ obj_xy,
    const float* __restrict__ strides,
    float* __restrict__ cx, float* __restrict__ cy) {
  const int G = 8;
  __shared__ float s_emb[G][EMBED];
  const int t = threadIdx.x;
  const int n0 = blockIdx.x * G;
  #pragma unroll
  for (int g = 0; g < G; ++g) s_emb[g][t] = obj_emb[(n0 + g) * EMBED + t];
  __syncthreads();

  float ax[G], ay[G];
  #pragma unroll
  for (int g = 0; g < G; ++g) { ax[g] = 0.f; ay[g] = 0.f; }

  const float2* wp = (const float2*)w_off;  // row = 256 float2
  for (int e = 0; e < EMBED; ++e) {
    float2 w = wp[e * 256 + t];
    #pragma unroll
    for (int g = 0; g < G; ++g) {
      float a = s_emb[g][e];
      ax[g] = fmaf(a, w.x, ax[g]);
      ay[g] = fmaf(a, w.y, ay[g]);
    }
  }
  const float bx = b_off[2 * t], by = b_off[2 * t + 1];
  #pragma unroll
  for (int g = 0; g < G; ++g) {
    const int n = n0 + g;
    const float st = strides[n];
    const float lx = obj_xy[2 * n]     + (ax[g] + bx) * st;
    const float ly = obj_xy[2 * n + 1] + (ay[g] + by) * st;
    const float gx = lx * (2.0f / (WW * 4)) - 1.0f;
    const float gy = ly * (2.0f / (HH * 4)) - 1.0f;
    const float ix = ((gx + 1.0f) * WW - 1.0f) * 0.5f;
    const float iy = ((gy + 1.0f) * HH - 1.0f) * 0.5f;
    cx[n * 256 + t] = ix;
    cy[n * 256 + t] = iy;
  }
}

// ---------------------------------------------------------------------------
// K-relayout: key_feat/value (img,c,y,x) f32 -> kvh (img,y,x,kv,c) f16.
// ---------------------------------------------------------------------------
__global__ __launch_bounds__(256) void k_relayout(
    const float* __restrict__ key_feat, const float* __restrict__ value,
    __half* __restrict__ kvh) {
  __shared__ float s[64][33];
  const int t = threadIdx.x;
  const int xt  = blockIdx.x;   // 0..4  (x tile of 32)
  const int y   = blockIdx.y;   // 0..159
  const int img = blockIdx.z;   // 0..3
  const int xl = t & 31, cgrp = t >> 5;   // load map: 8 c-groups x 32 x
  const int xw = t >> 3, cw = t & 7;      // write map: 32 x x 8 c-groups

  for (int kv = 0; kv < 2; ++kv) {
    const float* src = kv ? value : key_feat;
    for (int ct = 0; ct < 4; ++ct) {
      #pragma unroll
      for (int i = 0; i < 8; ++i) {
        const int c = ct * 64 + cgrp * 8 + i;
        s[cgrp * 8 + i][xl] =
            src[((size_t)(img * 256 + c)) * PLANE + y * WW + xt * 32 + xl];
      }
      __syncthreads();
      __half h8[8];
      #pragma unroll
      for (int j = 0; j < 8; ++j) h8[j] = __float2half(s[cw * 8 + j][xw]);
      const size_t ob = ((size_t)(img * PLANE + y * WW + xt * 32 + xw)) * 512
                        + kv * 256 + ct * 64 + cw * 8;
      *(int4*)(kvh + ob) = *(const int4*)h8;
      __syncthreads();
    }
  }
}

// ---------------------------------------------------------------------------
// helper: accumulate 8 f16 channels (one int4) scaled by w into acc[8]
// ---------------------------------------------------------------------------
__device__ __forceinline__ void acc8(int4 r, float w, float* acc) {
  const __half2* hp = (const __half2*)&r;
  #pragma unroll
  for (int i = 0; i < 4; ++i) {
    const float2 f = __half22float2(hp[i]);
    acc[2 * i]     = fmaf(w, f.x, acc[2 * i]);
    acc[2 * i + 1] = fmaf(w, f.y, acc[2 * i + 1]);
  }
}

// ---------------------------------------------------------------------------
// K2: sample from f16 HWC kv layout; writes v/a/mask/x2d outputs + attn (f16)
// ---------------------------------------------------------------------------
__global__ __launch_bounds__(256) void k_sample_hwc(
    const float* __restrict__ query, const __half* __restrict__ kvh,
    const float* __restrict__ x2d, const float* __restrict__ x2d_mask,
    const int* __restrict__ obj_img,
    const float* __restrict__ cx, const float* __restrict__ cy,
    float* __restrict__ o_vs, float* __restrict__ o_as,
    float* __restrict__ o_ms, float* __restrict__ o_x2,
    _Float16* __restrict__ attn_h) {
  __shared__ float s_q[256];
  __shared__ float s_v[NHD * NPT * 33];
  __shared__ float s_asm[256];

  const int n = blockIdx.x;
  const int t = threadIdx.x;
  const int h = t >> 5, p = t & 31;

  s_q[t] = query[n * 256 + t];
  const int img = obj_img[n];
  const float ix = cx[n * 256 + t];
  const float iy = cy[n * 256 + t];

  const float x0f = floorf(ix), y0f = floorf(iy);
  const float wx1 = ix - x0f, wy1 = iy - y0f;
  const int x0 = (int)x0f, y0 = (int)y0f;
  const int x1 = x0 + 1, y1 = y0 + 1;
  const int x0c = min(max(x0, 0), WW - 1), x1c = min(max(x1, 0), WW - 1);
  const int y0c = min(max(y0, 0), HH - 1), y1c = min(max(y1, 0), HH - 1);
  const float w00 = (1.f - wx1) * (1.f - wy1);
  const float w10 = wx1 * (1.f - wy1);
  const float w01 = (1.f - wx1) * wy1;
  const float w11 = wx1 * wy1;
  const int o00 = y0c * WW + x0c, o10 = y0c * WW + x1c;
  const int o01 = y1c * WW + x0c, o11 = y1c * WW + x1c;

  const size_t pb = (size_t)img * PLANE;
  const int4* base = (const int4*)kvh;  // pixel = 64 int4: k[0..31], v[32..63]
  const long b0 = ((long)(pb + o00)) * 64 + h * 4;
  const long b1 = ((long)(pb + o10)) * 64 + h * 4;
  const long b2 = ((long)(pb + o01)) * 64 + h * 4;
  const long b3 = ((long)(pb + o11)) * 64 + h * 4;
  __syncthreads();

  float a_acc = 0.f;
  float* svrow = &s_v[(h * NPT + p) * 33];
  float* vout = o_vs + (size_t)(n * NHD + h) * (HD * NPT) + p;
  #pragma unroll
  for (int ch = 0; ch < 4; ++ch) {
    const int4 k0 = base[b0 + ch],      k1 = base[b1 + ch];
    const int4 k2 = base[b2 + ch],      k3 = base[b3 + ch];
    const int4 v0 = base[b0 + 32 + ch], v1 = base[b1 + 32 + ch];
    const int4 v2 = base[b2 + 32 + ch], v3 = base[b3 + 32 + ch];
    float kc[8] = {0, 0, 0, 0, 0, 0, 0, 0};
    float vc[8] = {0, 0, 0, 0, 0, 0, 0, 0};
    acc8(k0, w00, kc); acc8(k1, w10, kc); acc8(k2, w01, kc); acc8(k3, w11, kc);
    acc8(v0, w00, vc); acc8(v1, w10, vc); acc8(v2, w01, vc); acc8(v3, w11, vc);
    #pragma unroll
    for (int j = 0; j < 8; ++j) {
      const int c = ch * 8 + j;
      a_acc = fmaf(s_q[h * HD + c], kc[j], a_acc);
      svrow[c] = vc[j];
      vout[c * NPT] = vc[j];
    }
  }

  const float a = a_acc * 0.17677669529663687f;  // 1/sqrt(32)
  o_as[n * 256 + t] = a;

  // x2d (2ch, border pad) from original f32
  const float* xb0 = x2d + (size_t)img * 2 * PLANE;
  const float* xb1 = xb0 + PLANE;
  const float x2v0 = w00 * xb0[o00] + w10 * xb0[o10] + w01 * xb0[o01] + w11 * xb0[o11];
  const float x2v1 = w00 * xb1[o00] + w10 * xb1[o10] + w01 * xb1[o01] + w11 * xb1[o11];
  o_x2[(size_t)n * 512 + h * 64 + p]      = x2v0;
  o_x2[(size_t)n * 512 + h * 64 + 32 + p] = x2v1;

  // mask (1ch, zeros pad)
  const float* mb = x2d_mask + (size_t)img * PLANE;
  const float m00 = (x0 >= 0 && x0 < WW && y0 >= 0 && y0 < HH) ? w00 : 0.f;
  const float m10 = (x1 >= 0 && x1 < WW && y0 >= 0 && y0 < HH) ? w10 : 0.f;
  const float m01 = (x0 >= 0 && x0 < WW && y1 >= 0 && y1 < HH) ? w01 : 0.f;
  const float m11 = (x1 >= 0 && x1 < WW && y1 >= 0 && y1 < HH) ? w11 : 0.f;
  const float m = m00 * mb[o00] + m10 * mb[o10] + m01 * mb[o01] + m11 * mb[o11];
  o_ms[n * 256 + t] = m;

  // softmax over p (32-lane groups)
  float mx = a;
  #pragma unroll
  for (int o = 16; o >= 1; o >>= 1) mx = fmaxf(mx, __shfl_xor(mx, o, 32));
  const float ev = expf(a - mx);
  float s = ev;
  #pragma unroll
  for (int o = 16; o >= 1; o >>= 1) s += __shfl_xor(s, o, 32);
  s_asm[t] = ev / s * m;
  __syncthreads();

  const int d = p;
  float o = 0.f;
  const float* svh = &s_v[h * NPT * 33];
  const float* amh = &s_asm[h * NPT];
  #pragma unroll
  for (int pp = 0; pp < NPT; ++pp) o = fmaf(amh[pp], svh[pp * 33 + d], o);
  attn_h[n * 256 + t] = (_Float16)o;
}

// ---------------------------------------------------------------------------
// K-cvtw: w[K][N] f32 -> wT[N][K] f16 (transpose + convert). Tile 32x32.
// ---------------------------------------------------------------------------
__global__ __launch_bounds__(256) void k_cvtw(
    const float* __restrict__ w, _Float16* __restrict__ wT, int K, int N) {
  __shared__ float s[32][33];
  const int t = threadIdx.x;
  const int k0 = blockIdx.x * 32, n0 = blockIdx.y * 32;
  const int nl = t & 31, kg = t >> 5;
  #pragma unroll
  for (int i = 0; i < 4; ++i) {
    const int k = kg * 4 + i;
    s[k][nl] = w[(size_t)(k0 + k) * N + n0 + nl];
  }
  __syncthreads();
  const int kl = t & 31, ng = t >> 5;
  #pragma unroll
  for (int i = 0; i < 4; ++i) {
    const int n = ng * 4 + i;
    wT[(size_t)(n0 + n) * K + k0 + kl] = (_Float16)s[kl][n];
  }
}

// ---------------------------------------------------------------------------
// MFMA GEMMs, f16 in / f32 acc. Wave tile 16x32 (2 N-tiles), block = 4 waves
// (M=64). Fragment maps (HW-verified m89/m120):
//   A[m=lane&15][k=quad*8+j], B[n=lane&15][k=quad*8+j] (pre-transposed BT),
//   D: col=lane&15, row=quad*4+reg.
// ---------------------------------------------------------------------------

// GEMM A: Y1[2048][256] = attn_h[2048][256] @ woT[256][256]^T
__global__ __launch_bounds__(256) void k_gemm_a(
    const _Float16* __restrict__ Ah, const _Float16* __restrict__ BT,
    float* __restrict__ C) {
  const int t = threadIdx.x;
  const int wv = t >> 6, lane = t & 63;
  const int r16 = lane & 15, quad = lane >> 4;
  const int m_base = blockIdx.x * 64 + wv * 16;
  const int n_base = blockIdx.y * 32;
  const _Float16* ap  = Ah + (size_t)(m_base + r16) * 256 + quad * 8;
  const _Float16* bp0 = BT + (size_t)(n_base + r16) * 256 + quad * 8;
  const _Float16* bp1 = bp0 + 16 * 256;
  f32x4 acc0 = {0.f, 0.f, 0.f, 0.f}, acc1 = {0.f, 0.f, 0.f, 0.f};
  #pragma unroll 4
  for (int kc = 0; kc < 256; kc += 32) {
    f16x8 a  = *(const f16x8*)(ap + kc);
    f16x8 b0 = *(const f16x8*)(bp0 + kc);
    f16x8 b1 = *(const f16x8*)(bp1 + kc);
    acc0 = __builtin_amdgcn_mfma_f32_16x16x32_f16(a, b0, acc0, 0, 0, 0);
    acc1 = __builtin_amdgcn_mfma_f32_16x16x32_f16(a, b1, acc1, 0, 0, 0);
  }
  float* cp = C + (size_t)(m_base + quad * 4) * 256 + n_base + r16;
  #pragma unroll
  for (int r = 0; r < 4; ++r) {
    cp[(size_t)r * 256]      = acc0[r];
    cp[(size_t)r * 256 + 16] = acc1[r];
  }
}

// GEMM B: Fh[2048][1024] = relu(Uh[2048][256] @ w1T[1024][256]^T + b1), f16 out
__global__ __launch_bounds__(256) void k_gemm_b(
    const _Float16* __restrict__ Ah, const _Float16* __restrict__ BT,
    const float* __restrict__ bias, _Float16* __restrict__ Fh) {
  const int t = threadIdx.x;
  const int wv = t >> 6, lane = t & 63;
  const int r16 = lane & 15, quad = lane >> 4;
  const int m_base = blockIdx.x * 64 + wv * 16;
  const int n_base = blockIdx.y * 32;
  const _Float16* ap  = Ah + (size_t)(m_base + r16) * 256 + quad * 8;
  const _Float16* bp0 = BT + (size_t)(n_base + r16) * 256 + quad * 8;
  const _Float16* bp1 = bp0 + 16 * 256;
  f32x4 acc0 = {0.f, 0.f, 0.f, 0.f}, acc1 = {0.f, 0.f, 0.f, 0.f};
  #pragma unroll 4
  for (int kc = 0; kc < 256; kc += 32) {
    f16x8 a  = *(const f16x8*)(ap + kc);
    f16x8 b0 = *(const f16x8*)(bp0 + kc);
    f16x8 b1 = *(const f16x8*)(bp1 + kc);
    acc0 = __builtin_amdgcn_mfma_f32_16x16x32_f16(a, b0, acc0, 0, 0, 0);
    acc1 = __builtin_amdgcn_mfma_f32_16x16x32_f16(a, b1, acc1, 0, 0, 0);
  }
  const float bb0 = bias[n_base + r16];
  const float bb1 = bias[n_base + 16 + r16];
  _Float16* fp = Fh + (size_t)(m_base + quad * 4) * 1024 + n_base + r16;
  #pragma unroll
  for (int r = 0; r < 4; ++r) {
    fp[(size_t)r * 1024]      = (_Float16)fmaxf(acc0[r] + bb0, 0.f);
    fp[(size_t)r * 1024 + 16] = (_Float16)fmaxf(acc1[r] + bb1, 0.f);
  }
}

// GEMM C: Y2[2048][256] = Fh[2048][1024] @ w2T[256][1024]^T
__global__ __launch_bounds__(256) void k_gemm_c(
    const _Float16* __restrict__ Ah, const _Float16* __restrict__ BT,
    float* __restrict__ C) {
  const int t = threadIdx.x;
  const int wv = t >> 6, lane = t & 63;
  const int r16 = lane & 15, quad = lane >> 4;
  const int m_base = blockIdx.x * 64 + wv * 16;
  const int n_base = blockIdx.y * 32;
  const _Float16* ap  = Ah + (size_t)(m_base + r16) * 1024 + quad * 8;
  const _Float16* bp0 = BT + (size_t)(n_base + r16) * 1024 + quad * 8;
  const _Float16* bp1 = bp0 + 16 * 1024;
  f32x4 acc0 = {0.f, 0.f, 0.f, 0.f}, acc1 = {0.f, 0.f, 0.f, 0.f};
  #pragma unroll 4
  for (int kc = 0; kc < 1024; kc += 32) {
    f16x8 a  = *(const f16x8*)(ap + kc);
    f16x8 b0 = *(const f16x8*)(bp0 + kc);
    f16x8 b1 = *(const f16x8*)(bp1 + kc);
    acc0 = __builtin_amdgcn_mfma_f32_16x16x32_f16(a, b0, acc0, 0, 0, 0);
    acc1 = __builtin_amdgcn_mfma_f32_16x16x32_f16(a, b1, acc1, 0, 0, 0);
  }
  float* cp = C + (size_t)(m_base + quad * 4) * 256 + n_base + r16;
  #pragma unroll
  for (int r = 0; r < 4; ++r) {
    cp[(size_t)r * 256]      = acc0[r];
    cp[(size_t)r * 256 + 16] = acc1[r];
  }
}

// ---------------------------------------------------------------------------
// K-ln1: U = LN1(Y1 + b_out + obj_emb); writes U (f32) and Uh (f16).
// ---------------------------------------------------------------------------
__global__ __launch_bounds__(256) void k_ln1(
    const float* __restrict__ Y1, const float* __restrict__ b_out,
    const float* __restrict__ obj_emb, const float* __restrict__ g,
    const float* __restrict__ b, float* __restrict__ U,
    _Float16* __restrict__ Uh) {
  __shared__ float s_y[8][EMBED + 8];
  const int t = threadIdx.x;
  const int m0 = blockIdx.x * 8;
  const float bo = b_out[t];
  #pragma unroll
  for (int r = 0; r < 8; ++r)
    s_y[r][t] = Y1[(size_t)(m0 + r) * EMBED + t] + bo
                + obj_emb[(size_t)(m0 + r) * EMBED + t];
  __syncthreads();
  const int wv = t >> 6, ln = t & 63;
  #pragma unroll
  for (int k = 0; k < 2; ++k) {
    const int rr = wv * 2 + k;
    const float v0 = s_y[rr][ln], v1 = s_y[rr][ln + 64];
    const float v2 = s_y[rr][ln + 128], v3 = s_y[rr][ln + 192];
    float sum = v0 + v1 + v2 + v3;
    #pragma unroll
    for (int o = 32; o >= 1; o >>= 1) sum += __shfl_xor(sum, o);
    const float mean = sum * (1.0f / EMBED);
    const float d0 = v0 - mean, d1 = v1 - mean, d2 = v2 - mean, d3 = v3 - mean;
    float ss = d0 * d0 + d1 * d1 + d2 * d2 + d3 * d3;
    #pragma unroll
    for (int o = 32; o >= 1; o >>= 1) ss += __shfl_xor(ss, o);
    const float rstd = rsqrtf(ss * (1.0f / EMBED) + LN_EPS);
    const size_t base = (size_t)(m0 + rr) * EMBED;
    const float o0 = d0 * rstd * g[ln]       + b[ln];
    const float o1 = d1 * rstd * g[ln + 64]  + b[ln + 64];
    const float o2 = d2 * rstd * g[ln + 128] + b[ln + 128];
    const float o3 = d3 * rstd * g[ln + 192] + b[ln + 192];
    U[base + ln] = o0;         Uh[base + ln] = (_Float16)o0;
    U[base + ln + 64] = o1;    Uh[base + ln + 64] = (_Float16)o1;
    U[base + ln + 128] = o2;   Uh[base + ln + 128] = (_Float16)o2;
    U[base + ln + 192] = o3;   Uh[base + ln + 192] = (_Float16)o3;
  }
}

// ---------------------------------------------------------------------------
// K-ln2: out = LN2(Y2 + b2 + U)
// ---------------------------------------------------------------------------
__global__ __launch_bounds__(256) void k_ln2(
    const float* __restrict__ Y2, const float* __restrict__ b2,
    const float* __restrict__ U, const float* __restrict__ g,
    const float* __restrict__ b, float* __restrict__ out) {
  __shared__ float s_y[8][EMBED + 8];
  const int t = threadIdx.x;
  const int m0 = blockIdx.x * 8;
  const float bb = b2[t];
  #pragma unroll
  for (int r = 0; r < 8; ++r)
    s_y[r][t] = Y2[(size_t)(m0 + r) * EMBED + t] + bb
                + U[(size_t)(m0 + r) * EMBED + t];
  __syncthreads();
  const int wv = t >> 6, ln = t & 63;
  #pragma unroll
  for (int k = 0; k < 2; ++k) {
    const int rr = wv * 2 + k;
    const float v0 = s_y[rr][ln], v1 = s_y[rr][ln + 64];
    const float v2 = s_y[rr][ln + 128], v3 = s_y[rr][ln + 192];
    float sum = v0 + v1 + v2 + v3;
    #pragma unroll
    for (int o = 32; o >= 1; o >>= 1) sum += __shfl_xor(sum, o);
    const float mean = sum * (1.0f / EMBED);
    const float d0 = v0 - mean, d1 = v1 - mean, d2 = v2 - mean, d3 = v3 - mean;
    float ss = d0 * d0 + d1 * d1 + d2 * d2 + d3 * d3;
    #pragma unroll
    for (int o = 32; o >= 1; o >>= 1) ss += __shfl_xor(ss, o);
    const float rstd = rsqrtf(ss * (1.0f / EMBED) + LN_EPS);
    const size_t base = (size_t)(m0 + rr) * EMBED;
    out[base + ln]       = d0 * rstd * g[ln]       + b[ln];
    out[base + ln + 64]  = d1 * rstd * g[ln + 64]  + b[ln + 64];
    out[base + ln + 128] = d2 * rstd * g[ln + 128] + b[ln + 128];
    out[base + ln + 192] = d3 * rstd * g[ln + 192] + b[ln + 192];
  }
}

// ---------------------------------------------------------------------------
extern "C" void kernel_launch(void* const* d_in, const int* in_sizes, int n_in,
                              void* d_out, int out_size, void* d_ws, size_t ws_size,
                              hipStream_t stream) {
  const float* query    = (const float*)d_in[0];
  const float* obj_emb  = (const float*)d_in[1];
  const float* key_feat = (const float*)d_in[2];
  const float* value    = (const float*)d_in[3];
  const float* x2d      = (const float*)d_in[4];
  const float* x2d_mask = (const float*)d_in[5];
  const float* obj_xy   = (const float*)d_in[6];
  const float* strides  = (const float*)d_in[7];
  const int*   obj_img  = (const int*)d_in[8];
  const float* w_off    = (const float*)d_in[9];
  const float* b_off    = (const float*)d_in[10];
  const float* w_out    = (const float*)d_in[11];
  const float* b_out    = (const float*)d_in[12];
  const float* ln1_g    = (const float*)d_in[13];
  const float* ln1_b    = (const float*)d_in[14];
  const float* w1       = (const float*)d_in[15];
  const float* b1       = (const float*)d_in[16];
  const float* w2       = (const float*)d_in[17];
  const float* b2       = (const float*)d_in[18];
  const float* ln2_g    = (const float*)d_in[19];
  const float* ln2_b    = (const float*)d_in[20];

  float* out = (float*)d_out;
  float* o_out = out;
  float* o_vs  = out + 524288;                       // (2048,8,32,32)
  float* o_as  = out + 524288 + 16777216;            // 17301504
  float* o_ms  = out + 524288 + 16777216 + 524288;   // 17825792
  float* o_x2  = out + 524288 + 16777216 + 1048576;  // 18350080

  // workspace plan (bytes):
  //   kvh      : 0          (104857600)
  //   cx / Y1  : B+0        (2 MB)   Y1 written after cx consumed
  //   cy / Y2  : B+2MB      (2 MB)   Y2 written after cy consumed
  //   U        : B+4MB      (2 MB)
  //   Fh       : B+6MB      (4 MB)
  //   attn_h   : B+10MB     (1 MB)
  //   Uh       : B+11MB     (1 MB)
  //   woT      : B+12MB     (128 KB)
  //   w1T      : +128KB     (512 KB)
  //   w2T      : +512KB     (512 KB)   total = 118,620,160 B
  char* wsb = (char*)d_ws;
  __half*    kvh    = (__half*)wsb;
  char* B = wsb + 104857600;
  float*     cx     = (float*)(B);
  float*     Y1     = (float*)(B);
  float*     cy     = (float*)(B + 2097152);
  float*     Y2     = (float*)(B + 2097152);
  float*     U      = (float*)(B + 4194304);
  _Float16*  Fh     = (_Float16*)(B + 6291456);
  _Float16*  attn_h = (_Float16*)(B + 10485760);
  _Float16*  Uh     = (_Float16*)(B + 11534336);
  _Float16*  woT    = (_Float16*)(B + 12582912);
  _Float16*  w1T    = (_Float16*)(B + 12582912 + 131072);
  _Float16*  w2T    = (_Float16*)(B + 12582912 + 131072 + 524288);

  k_offsets<<<NOBJ / 8, 256, 0, stream>>>(obj_emb, w_off, b_off, obj_xy,
                                          strides, cx, cy);
  k_relayout<<<dim3(5, HH, NUMIMG), 256, 0, stream>>>(key_feat, value, kvh);
  k_cvtw<<<dim3(8, 8), 256, 0, stream>>>(w_out, woT, 256, 256);
  k_cvtw<<<dim3(8, 32), 256, 0, stream>>>(w1, w1T, 256, 1024);
  k_cvtw<<<dim3(32, 8), 256, 0, stream>>>(w2, w2T, 1024, 256);
  k_sample_hwc<<<NOBJ, 256, 0, stream>>>(query, kvh, x2d, x2d_mask, obj_img,
                                         cx, cy, o_vs, o_as, o_ms, o_x2,
                                         attn_h);
  k_gemm_a<<<dim3(32, 8), 256, 0, stream>>>(attn_h, woT, Y1);
  k_ln1<<<NOBJ / 8, 256, 0, stream>>>(Y1, b_out, obj_emb, ln1_g, ln1_b, U, Uh);
  k_gemm_b<<<dim3(32, 32), 256, 0, stream>>>(Uh, w1T, b1, Fh);
  k_gemm_c<<<dim3(32, 8), 256, 0, stream>>>(Fh, w2T, Y2);
  k_ln2<<<NOBJ / 8, 256, 0, stream>>>(Y2, b2, U, ln2_g, ln2_b, o_out);
}